// Round 10
// baseline (535.088 us; speedup 1.0000x reference)
//
#include <hip/hip_runtime.h>
#include <hip/hip_bf16.h>

#define NROWS 131072
#define DDIM  64
#define KCODES 1024
#define HW    4096

// d_out is FLOAT32. Element offsets (reference return order):
#define OFF_ZQ   0ull
#define OFF_IDX  8388608ull
#define OFF_LOSS 8519680ull
#define OFF_EMB  8519681ull
#define OFF_NCS  8585217ull
#define OFF_EAVG 8586241ull

// d_out tail scratch (bytes from start of d_out), overlaying emb/ncs/eavg
// outputs which finalize1/2 rewrite after consuming:
//   wh bf16[65536] @ SCR_B0            (overlays emb-out, dead by finalize2)
//   wl bf16[65536] @ +131072           (overlays emb-out)
//   w2 f32[1024]   @ +262144           (overlays ncs-out, dead by finalize1)
//   es f32[65536]  @ +266240           (EXACTLY overlays eavg-out, 1:1)
#define SCR_B0   34078724ull
#define SCR_WLO  (SCR_B0 + 131072ull)
#define SCR_W2O  (SCR_B0 + 262144ull)
#define SCR_ESO  (SCR_B0 + 266240ull)

// ws layout (bytes): embT f32[65536] @0 | cnt f32[1024] @262144 |
// smooth f32[1024] @266240 | lossb f32[512] @270336  (total 272384 <= proven floor)
#define WSO_CNT    262144ull
#define WSO_SMOOTH 266240ull
#define WSO_LOSSB  270336ull

#define GAPTHR 7e-5f

typedef __attribute__((ext_vector_type(8))) short bf16x8;
typedef __attribute__((ext_vector_type(4))) float f32x4;

#define GLOAD_LDS16(gp, lp)                                                     \
    __builtin_amdgcn_global_load_lds(                                           \
        (const __attribute__((address_space(1))) void*)(gp),                    \
        (__attribute__((address_space(3))) void*)(lp), 16, 0, 0)

__device__ __forceinline__ float np_sumsq64(const float* v) {
#pragma clang fp contract(off)
    float r0 = v[0]*v[0], r1 = v[1]*v[1], r2 = v[2]*v[2], r3 = v[3]*v[3];
    float r4 = v[4]*v[4], r5 = v[5]*v[5], r6 = v[6]*v[6], r7 = v[7]*v[7];
    for (int i = 8; i < 64; i += 8) {
        r0 += v[i+0]*v[i+0]; r1 += v[i+1]*v[i+1];
        r2 += v[i+2]*v[i+2]; r3 += v[i+3]*v[i+3];
        r4 += v[i+4]*v[i+4]; r5 += v[i+5]*v[i+5];
        r6 += v[i+6]*v[i+6]; r7 += v[i+7]*v[i+7];
    }
    return ((r0+r1)+(r2+r3))+((r4+r5)+(r6+r7));
}
__device__ __forceinline__ float mul_rn(float a, float b) {
#pragma clang fp contract(off)
    return a * b;
}
__device__ __forceinline__ float add_rn(float a, float b) {
#pragma clang fp contract(off)
    return a + b;
}
__device__ __forceinline__ float sub2_rn(float s, float a) {
#pragma clang fp contract(off)
    return s - 2.0f * a;
}
__device__ __forceinline__ unsigned bf16rne(float v) {
    unsigned b = __float_as_uint(v);
    return (b + 0x7FFFu + ((b >> 16) & 1u)) >> 16;
}
__device__ __forceinline__ float bfu2f(unsigned short u) {
    return __uint_as_float(((unsigned)u) << 16);
}

__global__ __launch_bounds__(256) void prep_kernel(
        const float* __restrict__ emb, unsigned short* __restrict__ wh,
        unsigned short* __restrict__ wl, float* __restrict__ w2,
        float* __restrict__ embT) {
    __shared__ float tile[64][65];
    const int t = threadIdx.x;
    const int kb = blockIdx.x * 64;
#pragma unroll
    for (int i = 0; i < 16; ++i) {
        const int e = t + i * 256;
        const int kl = e >> 6, d = e & 63;
        const float v = emb[(size_t)(kb + kl) * DDIM + d];
        tile[kl][d] = v;
        const unsigned rh = bf16rne(v);
        const float lv = v - bfu2f((unsigned short)rh);
        wh[(size_t)(kb + kl) * DDIM + d] = (unsigned short)rh;
        wl[(size_t)(kb + kl) * DDIM + d] = (unsigned short)bf16rne(lv);
    }
    __syncthreads();
    if (t < 64) w2[kb + t] = np_sumsq64(&tile[t][0]);
#pragma unroll
    for (int i = 0; i < 16; ++i) {
        const int e = t + i * 256;
        const int d = e >> 6, kl = e & 63;
        embT[(size_t)d * KCODES + kb + kl] = tile[kl][d];
    }
}

__global__ __launch_bounds__(512, 4) void assign_kernel(
        const float* __restrict__ z, const float* __restrict__ emb,
        float* __restrict__ out,
        const unsigned short* __restrict__ wh, const unsigned short* __restrict__ wl,
        const float* __restrict__ w2, const float* __restrict__ embT,
        float* __restrict__ lossb) {
    __shared__ __attribute__((aligned(16))) unsigned short sx[256][72];
    __shared__ __attribute__((aligned(16))) unsigned short cb[2][2][4][512];
    __shared__ float w2s[KCODES];
    __shared__ unsigned k1s[256];
    __shared__ float redl[8];

    const int tid = threadIdx.x;
    const int lane = tid & 63, wid = tid >> 6;
    const int col = lane & 15, grp = lane >> 4;
    const int nb = blockIdx.x * 256;

    for (int i = tid; i < KCODES; i += 512) w2s[i] = w2[i];

    // stage x rows (2 threads/row, 32 d each), bf16-hi only
    {
        const int row = tid & 255, dh = tid >> 8;
        const int n = nb + row;
        const int w0 = n & 63, h0 = (n >> 6) & 63, b0 = n >> 12;
        const float* zb = z + (size_t)b0 * DDIM * HW + (size_t)dh * 32 * HW + h0 * 64 + w0;
        for (int j = 0; j < 32; ++j)
            sx[row][dh * 32 + j] = (unsigned short)bf16rne(zb[(size_t)j * HW]);
    }
    __syncthreads();

    bf16x8 fx[2][2];
#pragma unroll
    for (int rt = 0; rt < 2; ++rt)
#pragma unroll
        for (int kh = 0; kh < 2; ++kh)
            fx[rt][kh] = *(const bf16x8*)&sx[wid * 32 + rt * 16 + col][kh * 32 + grp * 8];

    const int pr = wid >> 2, sW = (wid >> 1) & 1, khW = wid & 1;
    const unsigned short* gsrc = (pr ? wl : wh) + khW * 32 + grp * 8
                               + (size_t)(sW * 16 + col) * DDIM;

    GLOAD_LDS16(gsrc, &cb[0][pr][sW * 2 + khW][0]);
    asm volatile("s_waitcnt vmcnt(0)" ::: "memory");
    __builtin_amdgcn_s_barrier();

    float m1[2] = {1e30f, 1e30f}, m2[2] = {1e30f, 1e30f};
    int   i1[2] = {0, 0};

    for (int rd = 0; rd < 32; ++rd) {
        const int cur = rd & 1;
        if (rd < 31)
            GLOAD_LDS16(gsrc + (size_t)(rd + 1) * 32 * DDIM,
                        &cb[cur ^ 1][pr][sW * 2 + khW][0]);
#pragma unroll
        for (int s = 0; s < 2; ++s) {
            const bf16x8 vh0 = *(const bf16x8*)&cb[cur][0][s * 2 + 0][lane * 8];
            const bf16x8 vh1 = *(const bf16x8*)&cb[cur][0][s * 2 + 1][lane * 8];
            const bf16x8 vl0 = *(const bf16x8*)&cb[cur][1][s * 2 + 0][lane * 8];
            const bf16x8 vl1 = *(const bf16x8*)&cb[cur][1][s * 2 + 1][lane * 8];
            const int cbase = rd * 32 + s * 16;
            const float4 w2v = *(const float4*)&w2s[cbase + grp * 4];
            const float* w2p = (const float*)&w2v;
#pragma unroll
            for (int rt = 0; rt < 2; ++rt) {
                f32x4 aA = {0.f, 0.f, 0.f, 0.f}, aB = {0.f, 0.f, 0.f, 0.f};
                aA = __builtin_amdgcn_mfma_f32_16x16x32_bf16(vh0, fx[rt][0], aA, 0, 0, 0);
                aA = __builtin_amdgcn_mfma_f32_16x16x32_bf16(vl0, fx[rt][0], aA, 0, 0, 0);
                aB = __builtin_amdgcn_mfma_f32_16x16x32_bf16(vh1, fx[rt][1], aB, 0, 0, 0);
                aB = __builtin_amdgcn_mfma_f32_16x16x32_bf16(vl1, fx[rt][1], aB, 0, 0, 0);
#pragma unroll
                for (int r = 0; r < 4; ++r) {
                    const float val = fmaf(-2.f, aA[r] + aB[r], w2p[r]);
                    const int code = cbase + grp * 4 + r;
                    const bool c1 = val < m1[rt];
                    m2[rt] = c1 ? m1[rt] : fminf(m2[rt], val);
                    i1[rt] = c1 ? code : i1[rt];
                    m1[rt] = c1 ? val : m1[rt];
                }
            }
        }
        asm volatile("s_waitcnt vmcnt(0) lgkmcnt(0)" ::: "memory");
        __builtin_amdgcn_s_barrier();
    }

#pragma unroll
    for (int rt = 0; rt < 2; ++rt) {
        for (int off = 16; off <= 32; off <<= 1) {
            const float o1 = __shfl_xor(m1[rt], off, 64);
            const float o2 = __shfl_xor(m2[rt], off, 64);
            const int   oi = __shfl_xor(i1[rt], off, 64);
            const float mx = fmaxf(m1[rt], o1);
            const bool take = (o1 < m1[rt]) || (o1 == m1[rt] && oi < i1[rt]);
            i1[rt] = take ? oi : i1[rt];
            m1[rt] = take ? o1 : m1[rt];
            m2[rt] = fminf(fminf(m2[rt], o2), mx);
        }
    }

    int k1rt[2];
    bool flag[2];
#pragma unroll
    for (int rt = 0; rt < 2; ++rt) {
        k1rt[rt] = i1[rt];
        flag[rt] = (grp == 0) && ((m2[rt] - m1[rt]) < GAPTHR);
    }

    // near-tie rows: full np-exact f32 rescan (coalesced via embT)
    for (int rt = 0; rt < 2; ++rt) {
        unsigned long long need = __ballot(flag[rt]);
        while (need) {
            const int src = __ffsll(need) - 1;
            need &= need - 1;
            const int nr = nb + wid * 32 + rt * 16 + src;
            const int wq = nr & 63, hq = (nr >> 6) & 63, bq = nr >> 12;
            const float xv = z[(size_t)bq * DDIM * HW + (size_t)lane * HW + hq * 64 + wq];
            const float p = mul_rn(xv, xv);
            float r = 0.f;
            for (int i = 0; i < 8; ++i) {
                const float t = __shfl(p, (i << 3) + (lane & 7), 64);
                r = add_rn(r, t);
            }
            const float s01 = add_rn(r, __shfl_xor(r, 1, 64));
            const float s03 = add_rn(s01, __shfl_xor(s01, 2, 64));
            const float s07 = add_rn(s03, __shfl_xor(s03, 4, 64));
            const float x2s = __shfl(s07, 0, 64);

            float acc[16];
#pragma unroll
            for (int j = 0; j < 16; ++j) acc[j] = 0.f;
            for (int d = 0; d < DDIM; ++d) {
                const float xd = __shfl(xv, d, 64);
                const float* ecol = embT + (size_t)d * KCODES + lane;
#pragma unroll
                for (int j = 0; j < 16; ++j)
                    acc[j] = fmaf(ecol[64 * j], xd, acc[j]);
            }
            float bv = 1e30f;
            int bk = KCODES;
#pragma unroll
            for (int j = 0; j < 16; ++j) {
                const int kk = lane + 64 * j;
                const float s  = add_rn(x2s, w2s[kk]);
                const float dv = sub2_rn(s, acc[j]);
                if (dv < bv) { bv = dv; bk = kk; }
            }
            for (int off = 32; off > 0; off >>= 1) {
                const float ov = __shfl_xor(bv, off, 64);
                const int   ok = __shfl_xor(bk, off, 64);
                if (ov < bv || (ov == bv && ok < bk)) { bv = ov; bk = ok; }
            }
            if (lane == src) k1rt[rt] = bk;
        }
    }

    if (grp == 0) {
#pragma unroll
        for (int rt = 0; rt < 2; ++rt)
            k1s[wid * 32 + rt * 16 + col] = (unsigned)k1rt[rt];
    }
    __syncthreads();

    // phase A: 2 threads/row (32 d each): idx, z_q, loss  (NO atomics)
    {
        const int rA = tid & 255, dhA = tid >> 8;
        const int nA = nb + rA;
        const int wA = nA & 63, hA = (nA >> 6) & 63, bA = nA >> 12;
        const unsigned myk = k1s[rA];
        if (dhA == 0)
            out[OFF_IDX + (size_t)(unsigned)nA] = (float)myk;
        const float* wrow = emb + (size_t)myk * DDIM + dhA * 32;
        float* ozb = out + (size_t)bA * DDIM * HW + (size_t)dhA * 32 * HW + hA * 64 + wA;
        float ls = 0.f;
#pragma unroll
        for (int j = 0; j < 32; j += 4) {
            const float4 wv = *(const float4*)(wrow + j);
            const ushort4 xu = *(const ushort4*)&sx[rA][dhA * 32 + j];
            ozb[(size_t)(j + 0) * HW] = wv.x;
            ozb[(size_t)(j + 1) * HW] = wv.y;
            ozb[(size_t)(j + 2) * HW] = wv.z;
            ozb[(size_t)(j + 3) * HW] = wv.w;
            const float a = bfu2f(xu.x) - wv.x, b = bfu2f(xu.y) - wv.y;
            const float c = bfu2f(xu.z) - wv.z, e = bfu2f(xu.w) - wv.w;
            ls = fmaf(a, a, ls); ls = fmaf(b, b, ls);
            ls = fmaf(c, c, ls); ls = fmaf(e, e, ls);
        }
#pragma unroll
        for (int off = 32; off > 0; off >>= 1) ls += __shfl_down(ls, off, 64);
        if (lane == 0) redl[wid] = ls;
    }
    __syncthreads();
    if (tid == 0) {
        float t = 0.f;
#pragma unroll
        for (int i = 0; i < 8; ++i) t += redl[i];
        lossb[blockIdx.x] = t;   // plain store, no atomic
    }
}

// one block per code: scan idx, gather-sum x in registers (zero atomics)
__global__ __launch_bounds__(256) void gather_kernel(
        const float* __restrict__ z, const float* __restrict__ idxf,
        float* __restrict__ es, float* __restrict__ cntf) {
    const int k = blockIdx.x;
    const int lane = threadIdx.x & 63, wid = threadIdx.x >> 6;
    const float fk = (float)k;
    float acc = 0.f;
    unsigned cnt = 0;
    for (int it = 0; it < 512; ++it) {
        const int base = wid * 32768 + it * 64;
        const float v = idxf[base + lane];
        unsigned long long m = __ballot(v == fk);
        cnt += (unsigned)__popcll(m);
        while (m) {
            const int src = __ffsll(m) - 1;
            m &= m - 1;
            const int n = base + src;
            const int b = n >> 12, hw = n & 4095;
            acc += z[((size_t)(b * 64 + lane)) * (size_t)HW + hw];
        }
    }
    __shared__ float sacc[4][64];
    __shared__ unsigned scnt[4];
    sacc[wid][lane] = acc;
    if (lane == 0) scnt[wid] = cnt;
    __syncthreads();
    if (wid == 0) {
        const float t = sacc[0][lane] + sacc[1][lane] + sacc[2][lane] + sacc[3][lane];
        es[(size_t)k * DDIM + lane] = t;
        if (lane == 0)
            cntf[k] = (float)(scnt[0] + scnt[1] + scnt[2] + scnt[3]);
    }
}

__global__ __launch_bounds__(1024) void finalize1_kernel(
        const float* __restrict__ cs, float* __restrict__ out,
        const float* __restrict__ cntf, const float* __restrict__ lossb,
        float* __restrict__ smoothed) {
    const int k = threadIdx.x;
    const float ncs = fmaf(0.01f, cntf[k], 0.99f * cs[k]);

    __shared__ float red[1024];
    red[k] = ncs;
    __syncthreads();
    for (int s = 512; s > 0; s >>= 1) {
        if (k < s) red[k] += red[k + s];
        __syncthreads();
    }
    const float nn = red[0];
    smoothed[k] = (ncs + 1e-5f) / (nn + 1024.f * 1e-5f) * nn;
    out[OFF_NCS + (size_t)k] = ncs;

    __syncthreads();
    red[k] = (k < 512) ? lossb[k] : 0.f;
    __syncthreads();
    for (int s = 512; s > 0; s >>= 1) {
        if (k < s) red[k] += red[k + s];
        __syncthreads();
    }
    if (k == 0) out[OFF_LOSS] = 0.25f * red[0] / 8388608.f;
}

__global__ __launch_bounds__(256) void finalize2_kernel(
        const float* __restrict__ eavg, float* __restrict__ out,
        const float* __restrict__ es, const float* __restrict__ smoothed) {
    const int e = blockIdx.x * 256 + threadIdx.x;   // 0..65535
    const float s = es[e];                          // read BEFORE overwrite
    const float ea = fmaf(0.01f, s, 0.99f * eavg[e]);
    out[OFF_EAVG + (size_t)e] = ea;                 // same address as es[e]
    out[OFF_EMB  + (size_t)e] = ea / smoothed[e >> 6];
}

extern "C" void kernel_launch(void* const* d_in, const int* in_sizes, int n_in,
                              void* d_out, int out_size, void* d_ws, size_t ws_size,
                              hipStream_t stream) {
    const float* z    = (const float*)d_in[0];
    const float* emb  = (const float*)d_in[1];
    const float* cs   = (const float*)d_in[2];
    const float* eavg = (const float*)d_in[3];
    float* out = (float*)d_out;

    unsigned short* wh = (unsigned short*)((char*)d_out + SCR_B0);
    unsigned short* wl = (unsigned short*)((char*)d_out + SCR_WLO);
    float*          w2 = (float*)((char*)d_out + SCR_W2O);
    float*          es = (float*)((char*)d_out + SCR_ESO);

    char* ws = (char*)d_ws;
    float* embT   = (float*)ws;
    float* cntf   = (float*)(ws + WSO_CNT);
    float* smooth = (float*)(ws + WSO_SMOOTH);
    float* lossb  = (float*)(ws + WSO_LOSSB);

    prep_kernel<<<16, 256, 0, stream>>>(emb, wh, wl, w2, embT);
    assign_kernel<<<NROWS / 256, 512, 0, stream>>>(z, emb, out, wh, wl, w2, embT, lossb);
    gather_kernel<<<KCODES, 256, 0, stream>>>(z, out + OFF_IDX, es, cntf);
    finalize1_kernel<<<1, 1024, 0, stream>>>(cs, out, cntf, lossb, smooth);
    finalize2_kernel<<<256, 256, 0, stream>>>(eavg, out, es, smooth);
}

// Round 11
// 474.076 us; speedup vs baseline: 1.1287x; 1.1287x over previous
//
#include <hip/hip_runtime.h>
#include <hip/hip_bf16.h>

#define NROWS 131072
#define DDIM  64
#define KCODES 1024
#define HW    4096

// d_out is FLOAT32. Element offsets (reference return order):
#define OFF_ZQ   0ull
#define OFF_IDX  8388608ull
#define OFF_LOSS 8519680ull
#define OFF_EMB  8519681ull
#define OFF_NCS  8585217ull
#define OFF_EAVG 8586241ull

// d_out tail scratch (overlays emb/ncs outputs; rewritten by finalize1/2 last):
#define SCR_B0   34078724ull                 // wh bf16[65536]
#define SCR_WLO  (SCR_B0 + 131072ull)        // wl bf16[65536]
#define SCR_W2O  (SCR_B0 + 262144ull)        // w2 f32[1024] (= ncs region)

// ws: embT @0 (256K) | kscr u32[131072] @262144 | lossb f32[512] @786432 |
//     smooth @788480 | cnt_p u32[P*1024] @792576 | esum_p f32[P*65536] @858112
#define WSO_KSCR   262144ull
#define WSO_LOSSB  786432ull
#define WSO_SMOOTH 788480ull
#define WSO_CNT    792576ull
#define WSO_ESUM   858112ull

#define GAPTHR 8e-5f

typedef __attribute__((ext_vector_type(8))) short bf16x8;
typedef __attribute__((ext_vector_type(4))) float f32x4;

__device__ __forceinline__ float np_sumsq64(const float* v) {
#pragma clang fp contract(off)
    float r0 = v[0]*v[0], r1 = v[1]*v[1], r2 = v[2]*v[2], r3 = v[3]*v[3];
    float r4 = v[4]*v[4], r5 = v[5]*v[5], r6 = v[6]*v[6], r7 = v[7]*v[7];
    for (int i = 8; i < 64; i += 8) {
        r0 += v[i+0]*v[i+0]; r1 += v[i+1]*v[i+1];
        r2 += v[i+2]*v[i+2]; r3 += v[i+3]*v[i+3];
        r4 += v[i+4]*v[i+4]; r5 += v[i+5]*v[i+5];
        r6 += v[i+6]*v[i+6]; r7 += v[i+7]*v[i+7];
    }
    return ((r0+r1)+(r2+r3))+((r4+r5)+(r6+r7));
}
__device__ __forceinline__ float mul_rn(float a, float b) {
#pragma clang fp contract(off)
    return a * b;
}
__device__ __forceinline__ float add_rn(float a, float b) {
#pragma clang fp contract(off)
    return a + b;
}
__device__ __forceinline__ float sub2_rn(float s, float a) {
#pragma clang fp contract(off)
    return s - 2.0f * a;
}
__device__ __forceinline__ unsigned bf16rne(float v) {
    unsigned b = __float_as_uint(v);
    return (b + 0x7FFFu + ((b >> 16) & 1u)) >> 16;
}
__device__ __forceinline__ float bfu2f(unsigned short u) {
    return __uint_as_float(((unsigned)u) << 16);
}
__device__ __forceinline__ unsigned flipf(float v) {
    unsigned b = __float_as_uint(v);
    return b ^ (0x80000000u | (unsigned)((int)b >> 31));
}
__device__ __forceinline__ float unflip_val(unsigned u) {
    u &= 0xFFFFFC00u;
    unsigned mask = 0x80000000u | (unsigned)((int)(~u) >> 31);
    return __uint_as_float(u ^ mask);
}

__global__ __launch_bounds__(256) void prep_kernel(
        const float* __restrict__ emb, unsigned short* __restrict__ wh,
        unsigned short* __restrict__ wl, float* __restrict__ w2,
        float* __restrict__ embT) {
    __shared__ float tile[64][65];
    const int t = threadIdx.x;
    const int kb = blockIdx.x * 64;
#pragma unroll
    for (int i = 0; i < 16; ++i) {
        const int e = t + i * 256;
        const int kl = e >> 6, d = e & 63;
        const float v = emb[(size_t)(kb + kl) * DDIM + d];
        tile[kl][d] = v;
        const unsigned rh = bf16rne(v);
        const float lv = v - bfu2f((unsigned short)rh);
        wh[(size_t)(kb + kl) * DDIM + d] = (unsigned short)rh;
        wl[(size_t)(kb + kl) * DDIM + d] = (unsigned short)bf16rne(lv);
    }
    __syncthreads();
    if (t < 64) w2[kb + t] = np_sumsq64(&tile[t][0]);
#pragma unroll
    for (int i = 0; i < 16; ++i) {
        const int e = t + i * 256;
        const int d = e >> 6, kl = e & 63;
        embT[(size_t)d * KCODES + kb + kl] = tile[kl][d];
    }
}

// ---------- score: barrier-free, register-double-buffered codebook ----------
#define CBLOAD(S, c)                                                          \
    { const size_t a_ = ((size_t)(((c) * 16 + col) * DDIM + grp * 8));        \
      wh##S##0 = *(const bf16x8*)(wh + a_);                                   \
      wh##S##1 = *(const bf16x8*)(wh + a_ + 32);                              \
      wl##S##0 = *(const bf16x8*)(wl + a_);                                   \
      wl##S##1 = *(const bf16x8*)(wl + a_ + 32); }

#define CBCOMP(S, c)                                                          \
    { const float4 w2v = *(const float4*)&w2s[(c) * 16 + grp * 4];            \
      const float* w2p = (const float*)&w2v;                                  \
      _Pragma("unroll")                                                       \
      for (int rt = 0; rt < 2; ++rt) {                                        \
        f32x4 aA = {0.f,0.f,0.f,0.f}, aB = {0.f,0.f,0.f,0.f};                 \
        aA = __builtin_amdgcn_mfma_f32_16x16x32_bf16(wh##S##0, fx[rt][0], aA, 0, 0, 0); \
        aA = __builtin_amdgcn_mfma_f32_16x16x32_bf16(wl##S##0, fx[rt][0], aA, 0, 0, 0); \
        aB = __builtin_amdgcn_mfma_f32_16x16x32_bf16(wh##S##1, fx[rt][1], aB, 0, 0, 0); \
        aB = __builtin_amdgcn_mfma_f32_16x16x32_bf16(wl##S##1, fx[rt][1], aB, 0, 0, 0); \
        _Pragma("unroll")                                                     \
        for (int r = 0; r < 4; ++r) {                                         \
          const float val = fmaf(-2.f, aA[r] + aB[r], w2p[r]);                \
          const unsigned u = (flipf(val) & 0xFFFFFC00u) |                     \
                             (unsigned)((c) * 16 + grp * 4 + r);              \
          const unsigned mx = m1[rt] > u ? m1[rt] : u;                        \
          m1[rt] = m1[rt] < u ? m1[rt] : u;                                   \
          m2[rt] = m2[rt] < mx ? m2[rt] : mx;                                 \
        } } }

__global__ __launch_bounds__(512, 4) void score_kernel(
        const float* __restrict__ z,
        const unsigned short* __restrict__ wh, const unsigned short* __restrict__ wl,
        const float* __restrict__ w2, unsigned* __restrict__ kscr) {
    __shared__ __attribute__((aligned(16))) unsigned short sxt[64][260]; // [d][row]
    __shared__ float w2s[KCODES];

    const int tid = threadIdx.x;
    const int lane = tid & 63, wid = tid >> 6;
    const int col = lane & 15, grp = lane >> 4;
    const int nb = blockIdx.x * 256;
    const int b = nb >> 12, hb = (nb >> 6) & 63;

    for (int i = tid; i < KCODES; i += 512) w2s[i] = w2[i];

    // stage x: contiguous float4 reads along w (1KB runs per wave per d)
    {
        const int h = lane >> 4, w4 = (lane & 15) * 4;
        const int row = h * 64 + w4;
#pragma unroll
        for (int it = 0; it < 8; ++it) {
            const int d = wid + 8 * it;
            const float4 v = *(const float4*)&z[((size_t)(b * 64 + d)) * HW + (hb + h) * 64 + w4];
            ushort4 u;
            u.x = (unsigned short)bf16rne(v.x);
            u.y = (unsigned short)bf16rne(v.y);
            u.z = (unsigned short)bf16rne(v.z);
            u.w = (unsigned short)bf16rne(v.w);
            *(ushort4*)&sxt[d][row] = u;
        }
    }
    __syncthreads();

    // x fragments (one-time scalar LDS gathers from transposed layout)
    bf16x8 fx[2][2];
#pragma unroll
    for (int rt = 0; rt < 2; ++rt)
#pragma unroll
        for (int kh = 0; kh < 2; ++kh) {
            const int row = wid * 32 + rt * 16 + col;
            bf16x8 f;
#pragma unroll
            for (int j = 0; j < 8; ++j)
                f[j] = (short)sxt[kh * 32 + grp * 8 + j][row];
            fx[rt][kh] = f;
        }

    unsigned m1[2] = {~0u, ~0u}, m2[2] = {~0u, ~0u};
    bf16x8 whA0, whA1, wlA0, wlA1, whB0, whB1, wlB0, wlB1;

    CBLOAD(A, 0)
    for (int c = 0; c < 64; c += 2) {
        CBLOAD(B, c + 1)
        CBCOMP(A, c)
        if (c + 2 < 64) CBLOAD(A, c + 2)
        CBCOMP(B, c + 1)
    }

    // merge top-2 across the 4 grp-lanes per row; emit k1 | flag
#pragma unroll
    for (int rt = 0; rt < 2; ++rt) {
        for (int off = 16; off <= 32; off <<= 1) {
            const unsigned o1 = (unsigned)__shfl_xor((int)m1[rt], off, 64);
            const unsigned o2 = (unsigned)__shfl_xor((int)m2[rt], off, 64);
            const unsigned mx = m1[rt] > o1 ? m1[rt] : o1;
            m1[rt] = m1[rt] < o1 ? m1[rt] : o1;
            const unsigned t2 = m2[rt] < o2 ? m2[rt] : o2;
            m2[rt] = t2 < mx ? t2 : mx;
        }
        if (grp == 0) {
            const bool fl = (unflip_val(m2[rt]) - unflip_val(m1[rt])) < GAPTHR;
            kscr[nb + wid * 32 + rt * 16 + col] =
                (m1[rt] & 1023u) | (fl ? 0x80000000u : 0u);
        }
    }
}

// ---------- output: rescan + idx + z_q(float4 runs) + loss + esum ----------
__global__ __launch_bounds__(512, 4) void output_kernel(
        const float* __restrict__ z, const float* __restrict__ emb,
        const float* __restrict__ embT, const float* __restrict__ w2,
        float* __restrict__ out, const unsigned* __restrict__ kscr,
        float* __restrict__ esum_p, unsigned* __restrict__ cnt_p,
        float* __restrict__ lossb, int pmask) {
    __shared__ __attribute__((aligned(16))) unsigned short sxt[64][260];
    __shared__ unsigned k1s[256];
    __shared__ float redl[8];

    const int tid = threadIdx.x;
    const int lane = tid & 63, wid = tid >> 6;
    const int nb = blockIdx.x * 256;
    const int b = nb >> 12, hb = (nb >> 6) & 63;

    // stage x (same pattern as score)
    {
        const int h = lane >> 4, w4 = (lane & 15) * 4;
        const int row = h * 64 + w4;
#pragma unroll
        for (int it = 0; it < 8; ++it) {
            const int d = wid + 8 * it;
            const float4 v = *(const float4*)&z[((size_t)(b * 64 + d)) * HW + (hb + h) * 64 + w4];
            ushort4 u;
            u.x = (unsigned short)bf16rne(v.x);
            u.y = (unsigned short)bf16rne(v.y);
            u.z = (unsigned short)bf16rne(v.z);
            u.w = (unsigned short)bf16rne(v.w);
            *(ushort4*)&sxt[d][row] = u;
        }
    }

    // k1 + np-exact rescan of flagged rows (wave owns 32 rows)
    unsigned kf = 0;
    if (lane < 32) kf = kscr[nb + wid * 32 + lane];
    int k1 = (int)(kf & 1023u);
    unsigned long long need = __ballot((lane < 32) && (kf & 0x80000000u));
    while (need) {
        const int src = __ffsll(need) - 1;
        need &= need - 1;
        const int nr = nb + wid * 32 + src;
        const int wq = nr & 63, hq = (nr >> 6) & 63, bq = nr >> 12;
        const float xv = z[(size_t)bq * DDIM * HW + (size_t)lane * HW + hq * 64 + wq];
        const float p = mul_rn(xv, xv);
        float r = 0.f;
        for (int i = 0; i < 8; ++i) {
            const float t = __shfl(p, (i << 3) + (lane & 7), 64);
            r = add_rn(r, t);
        }
        const float s01 = add_rn(r, __shfl_xor(r, 1, 64));
        const float s03 = add_rn(s01, __shfl_xor(s01, 2, 64));
        const float s07 = add_rn(s03, __shfl_xor(s03, 4, 64));
        const float x2s = __shfl(s07, 0, 64);

        float acc[16];
#pragma unroll
        for (int j = 0; j < 16; ++j) acc[j] = 0.f;
        for (int d = 0; d < DDIM; ++d) {
            const float xd = __shfl(xv, d, 64);
            const float* ecol = embT + (size_t)d * KCODES + lane;
#pragma unroll
            for (int j = 0; j < 16; ++j)
                acc[j] = fmaf(ecol[64 * j], xd, acc[j]);
        }
        float bv = 1e30f;
        int bk = KCODES;
#pragma unroll
        for (int j = 0; j < 16; ++j) {
            const int kk = lane + 64 * j;
            const float s  = add_rn(x2s, w2[kk]);
            const float dv = sub2_rn(s, acc[j]);
            if (dv < bv) { bv = dv; bk = kk; }
        }
        for (int off = 32; off > 0; off >>= 1) {
            const float ov = __shfl_xor(bv, off, 64);
            const int   ok = __shfl_xor(bk, off, 64);
            if (ov < bv || (ov == bv && ok < bk)) { bv = ov; bk = ok; }
        }
        if (lane == src) k1 = bk;
    }
    if (lane < 32) k1s[wid * 32 + lane] = (unsigned)k1;
    __syncthreads();

    const int part = blockIdx.x & pmask;

    // idx + cnt
    if (tid < 256) {
        const unsigned myk = k1s[tid];
        out[OFF_IDX + (size_t)(nb + tid)] = (float)myk;
        atomicAdd(&cnt_p[part * KCODES + myk], 1u);
    }

    // z_q (contiguous float4 stores along w) + loss
    float ls = 0.f;
    {
        const int h = lane >> 4, w4 = (lane & 15) * 4;
        const int row = h * 64 + w4;
#pragma unroll 2
        for (int it = 0; it < 8; ++it) {
            const int d = wid + 8 * it;
            float4 q;
            float* qp = (float*)&q;
#pragma unroll
            for (int j = 0; j < 4; ++j) {
                const unsigned k = k1s[row + j];
                const float wv = emb[(size_t)k * DDIM + d];
                qp[j] = wv;
                const float diff = bfu2f(sxt[d][row + j]) - wv;
                ls = fmaf(diff, diff, ls);
            }
            *(float4*)&out[((size_t)(b * 64 + d)) * HW + (hb + h) * 64 + w4] = q;
        }
    }
#pragma unroll
    for (int off = 32; off > 0; off >>= 1) ls += __shfl_down(ls, off, 64);
    if (lane == 0) redl[wid] = ls;
    __syncthreads();
    if (tid == 0) {
        float t = 0.f;
#pragma unroll
        for (int i = 0; i < 8; ++i) t += redl[i];
        lossb[blockIdx.x] = t;
    }

    // esum: lane = d, privatized atomics
    {
        float* ep = esum_p + (size_t)part * 65536;
        for (int r = 0; r < 32; ++r) {
            const int row = wid * 32 + r;
            atomicAdd(&ep[(size_t)k1s[row] * DDIM + lane], bfu2f(sxt[lane][row]));
        }
    }
}

__global__ __launch_bounds__(1024) void finalize1_kernel(
        const float* __restrict__ cs, float* __restrict__ out,
        const unsigned* __restrict__ cnt_p, const float* __restrict__ lossb,
        float* __restrict__ smoothed, int P) {
    const int k = threadIdx.x;
    unsigned c = 0;
    for (int p = 0; p < P; ++p) c += cnt_p[p * KCODES + k];
    const float ncs = fmaf(0.01f, (float)c, 0.99f * cs[k]);

    __shared__ float red[1024];
    red[k] = ncs;
    __syncthreads();
    for (int s = 512; s > 0; s >>= 1) {
        if (k < s) red[k] += red[k + s];
        __syncthreads();
    }
    const float nn = red[0];
    smoothed[k] = (ncs + 1e-5f) / (nn + 1024.f * 1e-5f) * nn;
    out[OFF_NCS + (size_t)k] = ncs;

    __syncthreads();
    red[k] = (k < 512) ? lossb[k] : 0.f;
    __syncthreads();
    for (int s = 512; s > 0; s >>= 1) {
        if (k < s) red[k] += red[k + s];
        __syncthreads();
    }
    if (k == 0) out[OFF_LOSS] = 0.25f * red[0] / 8388608.f;
}

__global__ __launch_bounds__(256) void finalize2_kernel(
        const float* __restrict__ eavg, float* __restrict__ out,
        const float* __restrict__ esum_p, const float* __restrict__ smoothed,
        int P) {
    const int e = blockIdx.x * 256 + threadIdx.x;
    float s = 0.f;
    for (int p = 0; p < P; ++p) s += esum_p[(size_t)p * 65536 + e];
    const float ea = fmaf(0.01f, s, 0.99f * eavg[e]);
    out[OFF_EAVG + (size_t)e] = ea;
    out[OFF_EMB  + (size_t)e] = ea / smoothed[e >> 6];
}

extern "C" void kernel_launch(void* const* d_in, const int* in_sizes, int n_in,
                              void* d_out, int out_size, void* d_ws, size_t ws_size,
                              hipStream_t stream) {
    const float* z    = (const float*)d_in[0];
    const float* emb  = (const float*)d_in[1];
    const float* cs   = (const float*)d_in[2];
    const float* eavg = (const float*)d_in[3];
    float* out = (float*)d_out;

    unsigned short* wh = (unsigned short*)((char*)d_out + SCR_B0);
    unsigned short* wl = (unsigned short*)((char*)d_out + SCR_WLO);
    float*          w2 = (float*)((char*)d_out + SCR_W2O);

    int P = 1;
    for (int p = 16; p >= 1; p >>= 1)
        if (ws_size >= WSO_ESUM + (size_t)p * 262144ull) { P = p; break; }

    char* ws = (char*)d_ws;
    float*    embT   = (float*)ws;
    unsigned* kscr   = (unsigned*)(ws + WSO_KSCR);
    float*    lossb  = (float*)(ws + WSO_LOSSB);
    float*    smooth = (float*)(ws + WSO_SMOOTH);
    unsigned* cnt_p  = (unsigned*)(ws + WSO_CNT);
    float*    esum_p = (float*)(ws + WSO_ESUM);

    (void)hipMemsetAsync(ws + WSO_CNT, 0, 65536 + (size_t)P * 262144ull, stream);
    prep_kernel<<<16, 256, 0, stream>>>(emb, wh, wl, w2, embT);
    score_kernel<<<NROWS / 256, 512, 0, stream>>>(z, wh, wl, w2, kscr);
    output_kernel<<<NROWS / 256, 512, 0, stream>>>(
        z, emb, embT, w2, out, kscr, esum_p, cnt_p, lossb, P - 1);
    finalize1_kernel<<<1, 1024, 0, stream>>>(cs, out, cnt_p, lossb, smooth, P);
    finalize2_kernel<<<256, 256, 0, stream>>>(eavg, out, esum_p, smooth, P);
}